// Round 3
// baseline (869.150 us; speedup 1.0000x reference)
//
#include <hip/hip_runtime.h>

#define GNUM  128
#define NPG   512
#define FDIM  128

// workspace layout (bytes)
#define OFF_A   0u              // 16 MB: A counts u4 [g][dst 512][src 512 nibbles]
#define OFF_WT  (16u<<20)       // 160 KB: Wt bf16 [l][n][k]
#define OFF_HTA (17u<<20)       // 16 MB: hT bf16 [g][feat 128][node 512]

typedef short bf16x8 __attribute__((ext_vector_type(8)));
typedef float f32x4  __attribute__((ext_vector_type(4)));
typedef unsigned short u16;

#define GLB_AS __attribute__((address_space(1)))
#define LDS_AS __attribute__((address_space(3)))

// async global->LDS DMA, 16 B per lane; LDS dest = wave-uniform base + lane*16
static __device__ inline void gload16(const void* g, void* l) {
    __builtin_amdgcn_global_load_lds((const GLB_AS unsigned*)g,
                                     (LDS_AS unsigned*)l, 16, 0, 0);
}

// round-to-nearest-even fp32 -> bf16
static __device__ inline unsigned bf1(float x) {
    unsigned b = __float_as_uint(x);
    return (b + 0x7fffu + ((b >> 16) & 1u)) >> 16;
}
static __device__ inline unsigned pack_bf2(float x, float y) {
    return bf1(x) | (bf1(y) << 16);
}
// 8 u4 counts (one u32) -> bf16x8 (exact: ints <= 15 are exact in bf16)
static __device__ inline bf16x8 cvt8n(unsigned x) {
    union { bf16x8 v; unsigned u[4]; } r;
#pragma unroll
    for (int i = 0; i < 4; ++i) {
        float f0 = (float)((x >> (8 * i)) & 0xFu);
        float f1 = (float)((x >> (8 * i + 4)) & 0xFu);
        r.u[i] = (__float_as_uint(f0) >> 16) | (__float_as_uint(f1) & 0xffff0000u);
    }
    return r.v;
}

// Fused prep: blocks [0,1024) transpose x fp32 [node][feat] -> hT bf16
// [g][feat][node] (linear); blocks [1024,1344) convert W -> Wt[l][n][k].
__global__ __launch_bounds__(256) void k_prep(const float* __restrict__ x,
                                              u16* __restrict__ hT,
                                              const float* __restrict__ W,
                                              u16* __restrict__ wt) {
    __shared__ char Cs[128 * 144];
    int t = threadIdx.x;
    int bid = blockIdx.x;
    if (bid >= 1024) {               // Wt path: 320 blocks
        int idx = (bid - 1024) * 256 + t;   // 5*16384
        int l = idx >> 14, r = idx & 16383;
        int n = r >> 7, k = r & 127;
        wt[idx] = (u16)bf1(W[(l << 14) + k * 128 + n]);
        return;
    }
    int m0 = bid * 64;
    int g = m0 >> 9, ml0 = m0 & 511;
#pragma unroll
    for (int it = 0; it < 8; ++it) {
        int i = t + 256 * it;                 // 2048 float4s
        int nl = i >> 5, fq = i & 31;
        float4 v = *(const float4*)(x + (size_t)(m0 + nl) * FDIM + fq * 4);
        *(u16*)(Cs + (fq * 4 + 0) * 144 + nl * 2) = (u16)bf1(v.x);
        *(u16*)(Cs + (fq * 4 + 1) * 144 + nl * 2) = (u16)bf1(v.y);
        *(u16*)(Cs + (fq * 4 + 2) * 144 + nl * 2) = (u16)bf1(v.z);
        *(u16*)(Cs + (fq * 4 + 3) * 144 + nl * 2) = (u16)bf1(v.w);
    }
    __syncthreads();
    u16* hg = hT + (size_t)g * 65536 + ml0;
#pragma unroll
    for (int j = 0; j < 4; ++j) {
        int idx = t + 256 * j;                // 1024 uint4s
        int f = idx >> 3, piece = idx & 7;
        uint4 v = *(const uint4*)(Cs + f * 144 + piece * 16);
        *(uint4*)((char*)(hg + (size_t)f * 512) + piece * 16) = v;
    }
}

// Dense adjacency (u4), single pass: one block per graph, 1024 thr, 128 KB LDS.
__global__ __launch_bounds__(1024) void k_adense(const int* __restrict__ src,
                                                 const int* __restrict__ dst,
                                                 unsigned* __restrict__ A4,
                                                 int halfE) {
    __shared__ uint4 cnt4[512 * 16];      // 128 KB
    unsigned* cnt = (unsigned*)cnt4;
    int g = blockIdx.x;
    int t = threadIdx.x;
#pragma unroll
    for (int j = 0; j < 8; ++j) cnt4[t + 1024 * j] = make_uint4(0u, 0u, 0u, 0u);
    __syncthreads();
    int epg = halfE / GNUM;               // 8192
#pragma unroll
    for (int r = 0; r < 2; ++r) {
        int base = r * halfE + g * epg;
        const int4* s4 = (const int4*)(src + base);
        const int4* d4 = (const int4*)(dst + base);
#pragma unroll
        for (int it = 0; it < 2; ++it) {
            int i = t + 1024 * it;
            int4 sv = s4[i], dv = d4[i];
            int s, d;
            s = sv.x & 511; d = dv.x & 511; atomicAdd(&cnt[d * 64 + (s >> 3)], 1u << ((s & 7) * 4));
            s = sv.y & 511; d = dv.y & 511; atomicAdd(&cnt[d * 64 + (s >> 3)], 1u << ((s & 7) * 4));
            s = sv.z & 511; d = dv.z & 511; atomicAdd(&cnt[d * 64 + (s >> 3)], 1u << ((s & 7) * 4));
            s = sv.w & 511; d = dv.w & 511; atomicAdd(&cnt[d * 64 + (s >> 3)], 1u << ((s & 7) * 4));
        }
    }
    __syncthreads();
    uint4* Ao = (uint4*)(A4 + (size_t)g * 512 * 64);
#pragma unroll
    for (int j = 0; j < 8; ++j) Ao[t + 1024 * j] = cnt4[t + 1024 * j];
}

// Round 15: one block per graph, h RESIDENT IN LDS for all 5 layers + readout.
// 128 blocks x 1024 thr (16 waves), 160 KB LDS: hT 128 KB (XOR-swizzled
// 16B blocks: bb' = bb ^ (f&7)) + 32 KB scratch (A double-buffer during
// phase-1; P-tile during phase-2 quarter-passes; readout scalars).
// No inter-block dependencies anywhere (round-2's coop-launch failure root
// cause removed). A streamed per layer (1 load/thread/chunk, vmcnt(1)
// counted wait, L2-resident after layer 0). Phase-2 per 128-row quarter:
// owner waves write P (with (1+eps)h self term) -> scratch, barrier, MFMA
// P@W from scratch + global wt, write h' straight back into LDS hT.
__global__ __launch_bounds__(1024) void k_gin(
        const u16* __restrict__ hT,
        const unsigned char* __restrict__ A,
        const u16* __restrict__ wt,
        const float* __restrict__ bias,
        const float* __restrict__ eps,
        const float* __restrict__ fc1w, const float* __restrict__ fc1b,
        const float* __restrict__ fc2w, const float* __restrict__ fc2b,
        float* __restrict__ out) {
    __shared__ uint4 smem16[163840 / 16];
    char* hTl = (char*)smem16;            // 131072 B: [f][node] swizzled
    char* scr = (char*)smem16 + 131072;   // 32768 B
    int t = threadIdx.x;
    int w = t >> 6, lane = t & 63;
    int q = lane >> 4, ln = lane & 15;
    int g = blockIdx.x;
    const unsigned char* Ab = A + (size_t)g * 131072;
    const u16* hgb = hT + (size_t)g * 65536;
    int rA0 = w * 32 + ln;                // wave rows rA0, rA0+16 (M=512)

    // initial hT load: 8192 16B slots; swizzle applied on the global source
#pragma unroll
    for (int j = 0; j < 8; ++j) {
        int p = t + 1024 * j;
        int f = p >> 6, bb = p & 63;
        gload16((const char*)hgb + (size_t)f * 1024 + ((bb ^ (f & 7)) << 4),
                hTl + p * 16);
    }
    const unsigned char* gA = Ab + (t >> 1) * 256 + (t & 1) * 16;  // + ch*32

    for (int l = 0; l < 5; ++l) {
        const u16* wl = wt + l * 16384;
        float ep = 1.f + eps[l];
        gload16(gA, scr + t * 16);        // A chunk 0 -> buf0
        f32x4 acc[2][8];
#pragma unroll
        for (int mt = 0; mt < 2; ++mt)
#pragma unroll
            for (int nt = 0; nt < 8; ++nt) acc[mt][nt] = (f32x4){0.f, 0.f, 0.f, 0.f};
#pragma unroll
        for (int ch = 0; ch < 8; ++ch) {
            char* Asc = scr + (ch & 1) * 16384;
            if (ch < 7) {
                gload16(gA + (ch + 1) * 32, scr + ((ch + 1) & 1) * 16384 + t * 16);
                asm volatile("s_waitcnt vmcnt(1)" ::: "memory");  // chunk ch landed
            } else {
                asm volatile("s_waitcnt vmcnt(0)" ::: "memory");
            }
            __builtin_amdgcn_s_barrier();     // chunk ch visible to all waves
#pragma unroll
            for (int kcL = 0; kcL < 2; ++kcL) {
                bf16x8 af0 = cvt8n(*(const unsigned*)(Asc + rA0 * 32 + kcL * 16 + q * 4));
                bf16x8 af1 = cvt8n(*(const unsigned*)(Asc + (rA0 + 16) * 32 + kcL * 16 + q * 4));
#pragma unroll
                for (int nt = 0; nt < 8; ++nt) {
                    int f = nt * 16 + ln;
                    int bb = (ch * 8 + ((kcL * 4 + q) ^ (f & 7))) << 4;
                    bf16x8 bf = *(const bf16x8*)(hTl + f * 1024 + bb);
                    acc[0][nt] = __builtin_amdgcn_mfma_f32_16x16x32_bf16(af0, bf, acc[0][nt], 0, 0, 0);
                    acc[1][nt] = __builtin_amdgcn_mfma_f32_16x16x32_bf16(af1, bf, acc[1][nt], 0, 0, 0);
                }
            }
            __builtin_amdgcn_s_barrier();     // reads of buf[ch&1] done (reuse)
        }
        // phase 2 in four 128-row quarter-passes (scratch = P-tile, 32 KB)
        for (int qp = 0; qp < 4; ++qp) {
            if ((w >> 2) == qp) {
                // P = pooled + (1+eps)*h_self -> scratch [r][f] bf16, XOR-swz
#pragma unroll
                for (int mt = 0; mt < 2; ++mt) {
                    int rl0 = (w & 3) * 32 + mt * 16 + q * 4;   // row in quarter
                    int node0 = qp * 128 + rl0;
#pragma unroll
                    for (int nt = 0; nt < 8; ++nt) {
                        int f = nt * 16 + ln;
                        const char* sp = hTl + f * 1024
                            + (((node0 >> 3) ^ (f & 7)) << 4) + (node0 & 7) * 2;
                        uint2 sv = *(const uint2*)sp;           // self h, 4 nodes
                        float s0 = __uint_as_float(sv.x << 16);
                        float s1 = __uint_as_float(sv.x & 0xffff0000u);
                        float s2 = __uint_as_float(sv.y << 16);
                        float s3 = __uint_as_float(sv.y & 0xffff0000u);
                        f32x4 a = acc[mt][nt];
                        int r0 = rl0 + 0, r1 = rl0 + 1, r2 = rl0 + 2, r3 = rl0 + 3;
                        *(u16*)(scr + r0 * 256 + ((f * 2) ^ ((r0 & 7) << 4))) = (u16)bf1(fmaf(ep, s0, a[0]));
                        *(u16*)(scr + r1 * 256 + ((f * 2) ^ ((r1 & 7) << 4))) = (u16)bf1(fmaf(ep, s1, a[1]));
                        *(u16*)(scr + r2 * 256 + ((f * 2) ^ ((r2 & 7) << 4))) = (u16)bf1(fmaf(ep, s2, a[2]));
                        *(u16*)(scr + r3 * 256 + ((f * 2) ^ ((r3 & 7) << 4))) = (u16)bf1(fmaf(ep, s3, a[3]));
                    }
                }
            }
            __syncthreads();                  // P visible
            if ((w >> 2) == qp) {
                f32x4 acc2[2][8];
#pragma unroll
                for (int mt = 0; mt < 2; ++mt)
#pragma unroll
                    for (int nt = 0; nt < 8; ++nt) acc2[mt][nt] = (f32x4){0.f, 0.f, 0.f, 0.f};
                int r0 = (w & 3) * 32 + ln;   // P rows r0, r0+16
                int xr = (r0 & 7) << 4;       // (r0+16)&7 == r0&7
#pragma unroll
                for (int ks = 0; ks < 4; ++ks) {
                    bf16x8 af0 = *(const bf16x8*)(scr + r0 * 256 + ((ks * 64 + q * 16) ^ xr));
                    bf16x8 af1 = *(const bf16x8*)(scr + (r0 + 16) * 256 + ((ks * 64 + q * 16) ^ xr));
#pragma unroll
                    for (int nt = 0; nt < 8; ++nt) {
                        bf16x8 bf = *(const bf16x8*)(wl + (size_t)(nt * 16 + ln) * 128 + ks * 32 + q * 8);
                        acc2[0][nt] = __builtin_amdgcn_mfma_f32_16x16x32_bf16(af0, bf, acc2[0][nt], 0, 0, 0);
                        acc2[1][nt] = __builtin_amdgcn_mfma_f32_16x16x32_bf16(af1, bf, acc2[1][nt], 0, 0, 0);
                    }
                }
                // h' = relu(.+bias) -> back into LDS hT (cols of this quarter)
#pragma unroll
                for (int mt = 0; mt < 2; ++mt) {
                    int rl0 = (w & 3) * 32 + mt * 16 + q * 4;
                    int node0 = qp * 128 + rl0;
#pragma unroll
                    for (int nt = 0; nt < 8; ++nt) {
                        int n = nt * 16 + ln;
                        float bv = bias[l * 128 + n];
                        f32x4 a = acc2[mt][nt];
                        char* op = hTl + n * 1024
                            + (((node0 >> 3) ^ (n & 7)) << 4) + (node0 & 7) * 2;
                        *(uint2*)op =
                            make_uint2(pack_bf2(fmaxf(a[0] + bv, 0.f), fmaxf(a[1] + bv, 0.f)),
                                       pack_bf2(fmaxf(a[2] + bv, 0.f), fmaxf(a[3] + bv, 0.f)));
                    }
                }
            }
            __syncthreads();                  // h' quarter committed
        }
    }
    // readout from LDS hT: hg[f] = row sum (block order irrelevant)
    float* hg = (float*)scr;
    float* zz = hg + 128;
    float* lg = zz + 128;
    if (t < 128) {
        float acc = 0.f;
        const char* row = hTl + (size_t)t * 1024;
#pragma unroll 4
        for (int i = 0; i < 64; ++i) {
            int bb = (i + (t & 63)) & 63;     // stagger banks
            uint4 u = *(const uint4*)(row + bb * 16);
            acc += __uint_as_float(u.x << 16) + __uint_as_float(u.x & 0xffff0000u);
            acc += __uint_as_float(u.y << 16) + __uint_as_float(u.y & 0xffff0000u);
            acc += __uint_as_float(u.z << 16) + __uint_as_float(u.z & 0xffff0000u);
            acc += __uint_as_float(u.w << 16) + __uint_as_float(u.w & 0xffff0000u);
        }
        hg[t] = acc;
    }
    __syncthreads();
    if (t < 128) {
        float a1 = fc1b[t];
#pragma unroll 4
        for (int k = 0; k < 128; ++k) a1 = fmaf(hg[k], fc1w[k * 128 + t], a1);
        zz[t] = fmaxf(a1, 0.f);
    }
    __syncthreads();
    if (t < 10) {
        float l2 = fc2b[t];
        for (int k = 0; k < 128; ++k) l2 = fmaf(zz[k], fc2w[k * 10 + t], l2);
        lg[t] = l2;
    }
    __syncthreads();
    if (t < 10) {
        float m = lg[0];
        for (int c = 1; c < 10; ++c) m = fmaxf(m, lg[c]);
        float ssum = 0.f;
        for (int c = 0; c < 10; ++c) ssum += expf(lg[c] - m);
        out[g * 10 + t] = expf(lg[t] - m) / ssum;
    }
}

extern "C" void kernel_launch(void* const* d_in, const int* in_sizes, int n_in,
                              void* d_out, int out_size, void* d_ws, size_t ws_size,
                              hipStream_t stream) {
    const float* x    = (const float*)d_in[0];
    const float* eps  = (const float*)d_in[1];
    const float* W    = (const float*)d_in[2];
    const float* b    = (const float*)d_in[3];
    const float* fc1w = (const float*)d_in[4];
    const float* fc1b = (const float*)d_in[5];
    const float* fc2w = (const float*)d_in[6];
    const float* fc2b = (const float*)d_in[7];
    const int*   src  = (const int*)d_in[8];
    const int*   dst  = (const int*)d_in[9];
    int E = in_sizes[8];
    int halfE = E >> 1;

    char* ws  = (char*)d_ws;
    unsigned char* Abuf = (unsigned char*)(ws + OFF_A);
    u16*  wtb = (u16*)(ws + OFF_WT);
    u16*  hta = (u16*)(ws + OFF_HTA);
    float* out = (float*)d_out;

    k_prep<<<1344, 256, 0, stream>>>(x, hta, W, wtb);
    k_adense<<<GNUM, 1024, 0, stream>>>(src, dst, (unsigned*)Abuf, halfE);
    k_gin<<<GNUM, 1024, 0, stream>>>(hta, Abuf, wtb, b, eps,
                                     fc1w, fc1b, fc2w, fc2b, out);
}

// Round 4
// 291.656 us; speedup vs baseline: 2.9800x; 2.9800x over previous
//
#include <hip/hip_runtime.h>

#define GNUM  128
#define NPG   512
#define FDIM  128

// workspace layout (bytes)
#define OFF_A   0u              // 16 MB: A counts u4 [g][dst 512][src 512 nibbles]
#define OFF_WT  (16u<<20)       // 160 KB: Wt bf16 [l][n][k]
#define OFF_HTA (17u<<20)       // 16 MB: hT bf16 [g][feat 128][node 512] (ping)
#define OFF_HTB (33u<<20)       // 16 MB: hT bf16 (pong)

typedef short bf16x8 __attribute__((ext_vector_type(8)));
typedef float f32x4  __attribute__((ext_vector_type(4)));
typedef unsigned short u16;

#define GLB_AS __attribute__((address_space(1)))
#define LDS_AS __attribute__((address_space(3)))

// async global->LDS DMA, 16 B per lane; LDS dest = wave-uniform base + lane*16
static __device__ inline void gload16(const void* g, void* l) {
    __builtin_amdgcn_global_load_lds((const GLB_AS unsigned*)g,
                                     (LDS_AS unsigned*)l, 16, 0, 0);
}

// round-to-nearest-even fp32 -> bf16
static __device__ inline unsigned bf1(float x) {
    unsigned b = __float_as_uint(x);
    return (b + 0x7fffu + ((b >> 16) & 1u)) >> 16;
}
static __device__ inline unsigned pack_bf2(float x, float y) {
    return bf1(x) | (bf1(y) << 16);
}
// 8 u4 counts (one u32) -> bf16x8 (exact: ints <= 15 are exact in bf16)
static __device__ inline bf16x8 cvt8n(unsigned x) {
    union { bf16x8 v; unsigned u[4]; } r;
#pragma unroll
    for (int i = 0; i < 4; ++i) {
        float f0 = (float)((x >> (8 * i)) & 0xFu);
        float f1 = (float)((x >> (8 * i + 4)) & 0xFu);
        r.u[i] = (__float_as_uint(f0) >> 16) | (__float_as_uint(f1) & 0xffff0000u);
    }
    return r.v;
}

// Fused prep: blocks [0,1024) transpose x fp32 [node][feat] -> hT bf16
// [g][feat][node]; blocks [1024,1344) convert W[l][k][n] fp32 -> Wt[l][n][k].
__global__ __launch_bounds__(256) void k_prep(const float* __restrict__ x,
                                              u16* __restrict__ hT,
                                              const float* __restrict__ W,
                                              u16* __restrict__ wt) {
    __shared__ char Cs[128 * 144];
    int t = threadIdx.x;
    int bid = blockIdx.x;
    if (bid >= 1024) {               // Wt path: 320 blocks
        int idx = (bid - 1024) * 256 + t;   // 5*16384
        int l = idx >> 14, r = idx & 16383;
        int n = r >> 7, k = r & 127;
        wt[idx] = (u16)bf1(W[(l << 14) + k * 128 + n]);
        return;
    }
    int m0 = bid * 64;
    int g = m0 >> 9, ml0 = m0 & 511;
#pragma unroll
    for (int it = 0; it < 8; ++it) {
        int i = t + 256 * it;                 // 2048 float4s
        int nl = i >> 5, fq = i & 31;
        float4 v = *(const float4*)(x + (size_t)(m0 + nl) * FDIM + fq * 4);
        *(u16*)(Cs + (fq * 4 + 0) * 144 + nl * 2) = (u16)bf1(v.x);
        *(u16*)(Cs + (fq * 4 + 1) * 144 + nl * 2) = (u16)bf1(v.y);
        *(u16*)(Cs + (fq * 4 + 2) * 144 + nl * 2) = (u16)bf1(v.z);
        *(u16*)(Cs + (fq * 4 + 3) * 144 + nl * 2) = (u16)bf1(v.w);
    }
    __syncthreads();
    u16* hg = hT + (size_t)g * 65536 + ml0;
#pragma unroll
    for (int j = 0; j < 4; ++j) {
        int idx = t + 256 * j;                // 1024 uint4s
        int f = idx >> 3, piece = idx & 7;
        uint4 v = *(const uint4*)(Cs + f * 144 + piece * 16);
        *(uint4*)((char*)(hg + (size_t)f * 512) + piece * 16) = v;
    }
}

// Dense adjacency (u4), single pass: one block per graph, 1024 thr, 128 KB LDS.
__global__ __launch_bounds__(1024) void k_adense(const int* __restrict__ src,
                                                 const int* __restrict__ dst,
                                                 unsigned* __restrict__ A4,
                                                 int halfE) {
    __shared__ uint4 cnt4[512 * 16];      // 128 KB
    unsigned* cnt = (unsigned*)cnt4;
    int g = blockIdx.x;
    int t = threadIdx.x;
#pragma unroll
    for (int j = 0; j < 8; ++j) cnt4[t + 1024 * j] = make_uint4(0u, 0u, 0u, 0u);
    __syncthreads();
    int epg = halfE / GNUM;               // 8192
#pragma unroll
    for (int r = 0; r < 2; ++r) {
        int base = r * halfE + g * epg;
        const int4* s4 = (const int4*)(src + base);
        const int4* d4 = (const int4*)(dst + base);
#pragma unroll
        for (int it = 0; it < 2; ++it) {
            int i = t + 1024 * it;
            int4 sv = s4[i], dv = d4[i];
            int s, d;
            s = sv.x & 511; d = dv.x & 511; atomicAdd(&cnt[d * 64 + (s >> 3)], 1u << ((s & 7) * 4));
            s = sv.y & 511; d = dv.y & 511; atomicAdd(&cnt[d * 64 + (s >> 3)], 1u << ((s & 7) * 4));
            s = sv.z & 511; d = dv.z & 511; atomicAdd(&cnt[d * 64 + (s >> 3)], 1u << ((s & 7) * 4));
            s = sv.w & 511; d = dv.w & 511; atomicAdd(&cnt[d * 64 + (s >> 3)], 1u << ((s & 7) * 4));
        }
    }
    __syncthreads();
    uint4* Ao = (uint4*)(A4 + (size_t)g * 512 * 64);
#pragma unroll
    for (int j = 0; j < 8; ++j) Ao[t + 1024 * j] = cnt4[t + 1024 * j];
}

// Round 16: occupancy fix on the verified round-1 structure.
// Grid 1024 = graph (128) x dq (8 slices of 64 dst rows); 256 thr, 4 waves.
// Per wave: 32 rows x 64 feats (acc[2][4] = 32 VGPR; B-read:MFMA ratio kept
// at 8:16). A lives in 32 VGPRs (loaded once per layer from L2; no A DMA,
// no A LDS). LDS 32 KB = 2 x 16 KB B buffers (depth-1 counted vmcnt(4));
// P-tile (64x272 = 17 KB) and Os (128x144 = 18 KB) alias the buffers after
// the K-loop. __launch_bounds__(256,4) -> 4 blocks/CU x 4 waves = 4
// waves/SIMD (2x round-1), grid 1024 = exact machine fill.
__global__ __launch_bounds__(256, 4) void k_layer(const u16* __restrict__ hT,
                                                  u16* __restrict__ hTo,
                                                  const unsigned char* __restrict__ A,
                                                  const u16* __restrict__ wt,
                                                  const float* __restrict__ bias,
                                                  const float* __restrict__ eps) {
    __shared__ uint4 smem16[32768 / 16];
    char* smem = (char*)smem16;
    char* Ps = smem;                      // P: 64 x 272 B; Os: 128 x 144 B
    int t = threadIdx.x;
    int w = t >> 6, lane = t & 63;
    int q = lane >> 4, ln = lane & 15;
    int g = blockIdx.x & 127, dq = blockIdx.x >> 7;   // dq 0..7
    const unsigned char* Ab = A + (size_t)g * 131072 + (size_t)dq * 64 * 256;
    const u16* hb = hT + (size_t)g * 65536;
    int rA0 = (w & 1) * 32 + ln;          // wave rows rA0, rA0+16 (local 0..63)
    int fh0 = (w >> 1) * 64;              // wave's feature half

    // A fragments: rows rA0/rA0+16, q-slice, 8 chunks x 2 kcL = 32 u32 VGPRs
    unsigned aA[32];
#pragma unroll
    for (int ch = 0; ch < 8; ++ch)
#pragma unroll
        for (int kcL = 0; kcL < 2; ++kcL)
#pragma unroll
            for (int h = 0; h < 2; ++h)
                aA[ch * 4 + kcL * 2 + h] = *(const unsigned*)
                    (Ab + (size_t)(rA0 + h * 16) * 256 + ch * 32 + kcL * 16 + q * 4);

    f32x4 acc[2][4];
#pragma unroll
    for (int mt = 0; mt < 2; ++mt)
#pragma unroll
        for (int nt = 0; nt < 4; ++nt) acc[mt][nt] = (f32x4){0.f, 0.f, 0.f, 0.f};

    // prologue: B chunk 0 -> buf0 (16 KB; slots XOR-swizzled on global src)
#pragma unroll
    for (int j = 0; j < 4; ++j) {
        int p = t + 256 * j; int f = p >> 3;
        gload16((const char*)hb + (size_t)f * 1024 + (((p & 7) ^ (f & 7)) << 4),
                smem + p * 16);
    }
#pragma unroll
    for (int ch = 0; ch < 8; ++ch) {
        char* Bsc = smem + (ch & 1) * 16384;
        if (ch < 7) {                          // prefetch chunk ch+1
            char* Bsn = smem + ((ch + 1) & 1) * 16384;
#pragma unroll
            for (int j = 0; j < 4; ++j) {
                int p = t + 256 * j; int f = p >> 3;
                gload16((const char*)hb + (size_t)f * 1024 + (ch + 1) * 128
                            + (((p & 7) ^ (f & 7)) << 4),
                        Bsn + p * 16);
            }
            asm volatile("s_waitcnt vmcnt(4)" ::: "memory");  // chunk ch landed
        } else {
            asm volatile("s_waitcnt vmcnt(0)" ::: "memory");
        }
        __builtin_amdgcn_s_barrier();          // chunk ch visible to all waves
#pragma unroll
        for (int kcL = 0; kcL < 2; ++kcL) {
            bf16x8 af0 = cvt8n(aA[ch * 4 + kcL * 2 + 0]);
            bf16x8 af1 = cvt8n(aA[ch * 4 + kcL * 2 + 1]);
#pragma unroll
            for (int nt = 0; nt < 4; ++nt) {
                int f = fh0 + nt * 16 + ln;
                int sB = f * 8 + ((kcL * 4 + q) ^ (f & 7));
                bf16x8 bf = *(const bf16x8*)(Bsc + sB * 16);
                acc[0][nt] = __builtin_amdgcn_mfma_f32_16x16x32_bf16(af0, bf, acc[0][nt], 0, 0, 0);
                acc[1][nt] = __builtin_amdgcn_mfma_f32_16x16x32_bf16(af1, bf, acc[1][nt], 0, 0, 0);
            }
        }
        __builtin_amdgcn_s_barrier();          // reads of buf[ch&1] done (reuse)
    }
    // P = pooled + (1+eps)*h_self -> bf16 P-tile [row][feat], stride 272
    float ep = 1.f + eps[0];
#pragma unroll
    for (int mt = 0; mt < 2; ++mt) {
        int rl0 = (w & 1) * 32 + mt * 16 + q * 4;   // C rows rl0..rl0+3
        int mb0 = dq * 64 + rl0;
#pragma unroll
        for (int nt = 0; nt < 4; ++nt) {
            int f = fh0 + nt * 16 + ln;
            uint2 sv = *(const uint2*)(hb + (size_t)f * 512 + mb0);   // self h
            float s0 = __uint_as_float(sv.x << 16);
            float s1 = __uint_as_float(sv.x & 0xffff0000u);
            float s2 = __uint_as_float(sv.y << 16);
            float s3 = __uint_as_float(sv.y & 0xffff0000u);
            f32x4 a = acc[mt][nt];
            *(u16*)(Ps + (rl0 + 0) * 272 + f * 2) = (u16)bf1(fmaf(ep, s0, a[0]));
            *(u16*)(Ps + (rl0 + 1) * 272 + f * 2) = (u16)bf1(fmaf(ep, s1, a[1]));
            *(u16*)(Ps + (rl0 + 2) * 272 + f * 2) = (u16)bf1(fmaf(ep, s2, a[2]));
            *(u16*)(Ps + (rl0 + 3) * 272 + f * 2) = (u16)bf1(fmaf(ep, s3, a[3]));
        }
    }
    __syncthreads();                          // P visible to all waves
    // Phase 2: h'(64x128) = relu(P @ W + b); A-frags from Ps, B from Wt (L1)
    f32x4 acc2[2][4];
#pragma unroll
    for (int mt = 0; mt < 2; ++mt)
#pragma unroll
        for (int nt = 0; nt < 4; ++nt) acc2[mt][nt] = (f32x4){0.f, 0.f, 0.f, 0.f};
#pragma unroll
    for (int ks = 0; ks < 4; ++ks) {
        bf16x8 af0 = *(const bf16x8*)(Ps + rA0 * 272 + ks * 64 + q * 16);
        bf16x8 af1 = *(const bf16x8*)(Ps + (rA0 + 16) * 272 + ks * 64 + q * 16);
#pragma unroll
        for (int nt = 0; nt < 4; ++nt) {
            int n = fh0 + nt * 16 + ln;
            bf16x8 bf = *(const bf16x8*)(wt + (size_t)n * 128 + ks * 32 + q * 8);
            acc2[0][nt] = __builtin_amdgcn_mfma_f32_16x16x32_bf16(af0, bf, acc2[0][nt], 0, 0, 0);
            acc2[1][nt] = __builtin_amdgcn_mfma_f32_16x16x32_bf16(af1, bf, acc2[1][nt], 0, 0, 0);
        }
    }
    __syncthreads();                          // all P reads done; reuse as Os
    // epilogue: relu + bias, stage transposed [out-feat][64 nodes], stride 144
#pragma unroll
    for (int mt = 0; mt < 2; ++mt) {
        int rl0 = (w & 1) * 32 + mt * 16 + q * 4;
#pragma unroll
        for (int nt = 0; nt < 4; ++nt) {
            int n = fh0 + nt * 16 + ln;
            float bv = bias[n];
            f32x4 a = acc2[mt][nt];
            *(uint2*)(Ps + n * 144 + rl0 * 2) =
                make_uint2(pack_bf2(fmaxf(a[0] + bv, 0.f), fmaxf(a[1] + bv, 0.f)),
                           pack_bf2(fmaxf(a[2] + bv, 0.f), fmaxf(a[3] + bv, 0.f)));
        }
    }
    __syncthreads();
    u16* ho = hTo + (size_t)g * 65536 + dq * 64;
#pragma unroll
    for (int j = 0; j < 4; ++j) {
        int idx = t + 256 * j;                // 1024 uint4s: 128 f x 128 B
        int f = idx >> 3, piece = idx & 7;
        uint4 v = *(const uint4*)(Ps + f * 144 + piece * 16);
        *(uint4*)((char*)(ho + (size_t)f * 512) + piece * 16) = v;
    }
}

// readout from hT: hg[f] = row-sum; z = relu(hg@fc1+b1); softmax(z@fc2+b2)
__global__ __launch_bounds__(128) void k_r(const u16* __restrict__ hT,
                                           const float* __restrict__ fc1w,
                                           const float* __restrict__ fc1b,
                                           const float* __restrict__ fc2w,
                                           const float* __restrict__ fc2b,
                                           float* __restrict__ out) {
    __shared__ float hg[128], z[128], lg[10];
    int g = blockIdx.x, t = threadIdx.x;
    const uint4* row = (const uint4*)(hT + (size_t)g * 65536 + (size_t)t * 512);
    float acc = 0.f;
#pragma unroll 4
    for (int i = 0; i < 64; ++i) {
        uint4 u = row[i];
        acc += __uint_as_float(u.x << 16) + __uint_as_float(u.x & 0xffff0000u);
        acc += __uint_as_float(u.y << 16) + __uint_as_float(u.y & 0xffff0000u);
        acc += __uint_as_float(u.z << 16) + __uint_as_float(u.z & 0xffff0000u);
        acc += __uint_as_float(u.w << 16) + __uint_as_float(u.w & 0xffff0000u);
    }
    hg[t] = acc;
    __syncthreads();
    float a1 = fc1b[t];
#pragma unroll 4
    for (int k = 0; k < 128; ++k) a1 = fmaf(hg[k], fc1w[k * 128 + t], a1);
    z[t] = fmaxf(a1, 0.f);
    __syncthreads();
    if (t < 10) {
        float l2 = fc2b[t];
        for (int k = 0; k < 128; ++k) l2 = fmaf(z[k], fc2w[k * 10 + t], l2);
        lg[t] = l2;
    }
    __syncthreads();
    if (t < 10) {
        float m = lg[0];
        for (int c = 1; c < 10; ++c) m = fmaxf(m, lg[c]);
        float ssum = 0.f;
        for (int c = 0; c < 10; ++c) ssum += expf(lg[c] - m);
        out[g * 10 + t] = expf(lg[t] - m) / ssum;
    }
}

extern "C" void kernel_launch(void* const* d_in, const int* in_sizes, int n_in,
                              void* d_out, int out_size, void* d_ws, size_t ws_size,
                              hipStream_t stream) {
    const float* x    = (const float*)d_in[0];
    const float* eps  = (const float*)d_in[1];
    const float* W    = (const float*)d_in[2];
    const float* b    = (const float*)d_in[3];
    const float* fc1w = (const float*)d_in[4];
    const float* fc1b = (const float*)d_in[5];
    const float* fc2w = (const float*)d_in[6];
    const float* fc2b = (const float*)d_in[7];
    const int*   src  = (const int*)d_in[8];
    const int*   dst  = (const int*)d_in[9];
    int E = in_sizes[8];
    int halfE = E >> 1;

    char* ws  = (char*)d_ws;
    unsigned char* Abuf = (unsigned char*)(ws + OFF_A);
    u16*  wtb = (u16*)(ws + OFF_WT);
    u16*  hta = (u16*)(ws + OFF_HTA);
    u16*  htb = (u16*)(ws + OFF_HTB);
    float* out = (float*)d_out;

    k_prep<<<1344, 256, 0, stream>>>(x, hta, W, wtb);
    k_adense<<<GNUM, 1024, 0, stream>>>(src, dst, (unsigned*)Abuf, halfE);

    u16* cur = hta;
    u16* nxt = htb;
    for (int l = 0; l < 5; ++l) {
        k_layer<<<GNUM * 8, 256, 0, stream>>>(cur, nxt, Abuf,
                                              wtb + l * 128 * 128, b + l * 128, eps + l);
        u16* tmp = cur; cur = nxt; nxt = tmp;
    }
    k_r<<<GNUM, 128, 0, stream>>>(cur, fc1w, fc1b, fc2w, fc2b, out);
}

// Round 5
// 282.614 us; speedup vs baseline: 3.0754x; 1.0320x over previous
//
#include <hip/hip_runtime.h>

#define GNUM  128
#define NPG   512
#define FDIM  128

// workspace layout (bytes)
#define OFF_A   0u              // 16 MB: A counts u4 [g][dst 512][src 512 nibbles]
#define OFF_WT  (16u<<20)       // 160 KB: Wt bf16 [l][n][k]
#define OFF_HTA (17u<<20)       // 16 MB: hT bf16 [g][feat 128][node 512] (ping)
#define OFF_HTB (33u<<20)       // 16 MB: hT bf16 (pong)

typedef short bf16x8 __attribute__((ext_vector_type(8)));
typedef float f32x4  __attribute__((ext_vector_type(4)));
typedef unsigned short u16;

#define GLB_AS __attribute__((address_space(1)))
#define LDS_AS __attribute__((address_space(3)))

// async global->LDS DMA, 16 B per lane; LDS dest = wave-uniform base + lane*16
static __device__ inline void gload16(const void* g, void* l) {
    __builtin_amdgcn_global_load_lds((const GLB_AS unsigned*)g,
                                     (LDS_AS unsigned*)l, 16, 0, 0);
}

// round-to-nearest-even fp32 -> bf16
static __device__ inline unsigned bf1(float x) {
    unsigned b = __float_as_uint(x);
    return (b + 0x7fffu + ((b >> 16) & 1u)) >> 16;
}
static __device__ inline unsigned pack_bf2(float x, float y) {
    return bf1(x) | (bf1(y) << 16);
}
// 8 u4 counts (one u32) -> bf16x8 (exact: ints <= 15 are exact in bf16)
static __device__ inline bf16x8 cvt8n(unsigned x) {
    union { bf16x8 v; unsigned u[4]; } r;
#pragma unroll
    for (int i = 0; i < 4; ++i) {
        float f0 = (float)((x >> (8 * i)) & 0xFu);
        float f1 = (float)((x >> (8 * i + 4)) & 0xFu);
        r.u[i] = (__float_as_uint(f0) >> 16) | (__float_as_uint(f1) & 0xffff0000u);
    }
    return r.v;
}

// Fused prep: blocks [0,1024) transpose x fp32 [node][feat] -> hT bf16
// [g][feat][node]; blocks [1024,1344) convert W[l][k][n] fp32 -> Wt[l][n][k].
__global__ __launch_bounds__(256) void k_prep(const float* __restrict__ x,
                                              u16* __restrict__ hT,
                                              const float* __restrict__ W,
                                              u16* __restrict__ wt) {
    __shared__ char Cs[128 * 144];
    int t = threadIdx.x;
    int bid = blockIdx.x;
    if (bid >= 1024) {               // Wt path: 320 blocks
        int idx = (bid - 1024) * 256 + t;   // 5*16384
        int l = idx >> 14, r = idx & 16383;
        int n = r >> 7, k = r & 127;
        wt[idx] = (u16)bf1(W[(l << 14) + k * 128 + n]);
        return;
    }
    int m0 = bid * 64;
    int g = m0 >> 9, ml0 = m0 & 511;
#pragma unroll
    for (int it = 0; it < 8; ++it) {
        int i = t + 256 * it;                 // 2048 float4s
        int nl = i >> 5, fq = i & 31;
        float4 v = *(const float4*)(x + (size_t)(m0 + nl) * FDIM + fq * 4);
        *(u16*)(Cs + (fq * 4 + 0) * 144 + nl * 2) = (u16)bf1(v.x);
        *(u16*)(Cs + (fq * 4 + 1) * 144 + nl * 2) = (u16)bf1(v.y);
        *(u16*)(Cs + (fq * 4 + 2) * 144 + nl * 2) = (u16)bf1(v.z);
        *(u16*)(Cs + (fq * 4 + 3) * 144 + nl * 2) = (u16)bf1(v.w);
    }
    __syncthreads();
    u16* hg = hT + (size_t)g * 65536 + ml0;
#pragma unroll
    for (int j = 0; j < 4; ++j) {
        int idx = t + 256 * j;                // 1024 uint4s
        int f = idx >> 3, piece = idx & 7;
        uint4 v = *(const uint4*)(Cs + f * 144 + piece * 16);
        *(uint4*)((char*)(hg + (size_t)f * 512) + piece * 16) = v;
    }
}

// Dense adjacency (u4), single pass: one block per graph, 1024 thr, 128 KB LDS.
__global__ __launch_bounds__(1024) void k_adense(const int* __restrict__ src,
                                                 const int* __restrict__ dst,
                                                 unsigned* __restrict__ A4,
                                                 int halfE) {
    __shared__ uint4 cnt4[512 * 16];      // 128 KB
    unsigned* cnt = (unsigned*)cnt4;
    int g = blockIdx.x;
    int t = threadIdx.x;
#pragma unroll
    for (int j = 0; j < 8; ++j) cnt4[t + 1024 * j] = make_uint4(0u, 0u, 0u, 0u);
    __syncthreads();
    int epg = halfE / GNUM;               // 8192
#pragma unroll
    for (int r = 0; r < 2; ++r) {
        int base = r * halfE + g * epg;
        const int4* s4 = (const int4*)(src + base);
        const int4* d4 = (const int4*)(dst + base);
#pragma unroll
        for (int it = 0; it < 2; ++it) {
            int i = t + 1024 * it;
            int4 sv = s4[i], dv = d4[i];
            int s, d;
            s = sv.x & 511; d = dv.x & 511; atomicAdd(&cnt[d * 64 + (s >> 3)], 1u << ((s & 7) * 4));
            s = sv.y & 511; d = dv.y & 511; atomicAdd(&cnt[d * 64 + (s >> 3)], 1u << ((s & 7) * 4));
            s = sv.z & 511; d = dv.z & 511; atomicAdd(&cnt[d * 64 + (s >> 3)], 1u << ((s & 7) * 4));
            s = sv.w & 511; d = dv.w & 511; atomicAdd(&cnt[d * 64 + (s >> 3)], 1u << ((s & 7) * 4));
        }
    }
    __syncthreads();
    uint4* Ao = (uint4*)(A4 + (size_t)g * 512 * 64);
#pragma unroll
    for (int j = 0; j < 8; ++j) Ao[t + 1024 * j] = cnt4[t + 1024 * j];
}

// Round 17: staging-bandwidth fix. k_layer time scales with staged B bytes
// (r1: 4 blk/graph = 64 MB -> ~37 us/layer; r4: 8 blk/graph = 128 MB ->
// ~46 us/layer). So: 2 blocks/graph (grid 256 = 1 block/CU), 512 thr
// (8 waves), 256 dst rows per block. B-panel (graph hT, 128 KB) staged
// twice per graph instead of 4x: 32 MB+16 MB A per layer. Per-CU staging
// per chunk-step: 16 KB (was 40 KB), compute per SIMD unchanged (2 waves x
// 32 MFMA). A in 32 VGPRs (loaded once per layer, no redundancy; both
// blocks of a graph on one XCD: bid, bid+128 -> same L2). Depth-2
// counted-vmcnt B pipeline, 3 x 16 KB buffers; P-tile 256 x 272 B = 68 KB
// in its own region. LDS 116 KB, 1 block/CU. Per-element math order is
// bit-identical to round 1 (same fragments, same MFMA sequence).
__global__ __launch_bounds__(512, 2) void k_layer(const u16* __restrict__ hT,
                                                  u16* __restrict__ hTo,
                                                  const unsigned char* __restrict__ A,
                                                  const u16* __restrict__ wt,
                                                  const float* __restrict__ bias,
                                                  const float* __restrict__ eps) {
    // Bs[i] = smem + i*16384, i<3  [0, 49152)
    // Ps    = smem + 49152: P 256 x 272 = 69632; Os 128 x 528 = 67584 (alias)
    __shared__ uint4 smem16[118784 / 16];
    char* smem = (char*)smem16;
    char* Ps = smem + 49152;
    int t = threadIdx.x;                  // 0..511
    int w = t >> 6, lane = t & 63;
    int q = lane >> 4, ln = lane & 15;
    int g = blockIdx.x & 127, hf = blockIdx.x >> 7;   // hf 0..1
    const unsigned char* Ab = A + (size_t)g * 131072 + (size_t)hf * 65536;
    const u16* hb = hT + (size_t)g * 65536;
    int rA0 = w * 32 + ln;                // local rows rA0, rA0+16 (0..255)

    // A fragments: rows rA0/rA0+16, q-slice, 8 chunks x 2 kcL = 32 u32 VGPRs
    unsigned aA[32];
#pragma unroll
    for (int ch = 0; ch < 8; ++ch)
#pragma unroll
        for (int kcL = 0; kcL < 2; ++kcL)
#pragma unroll
            for (int h = 0; h < 2; ++h)
                aA[ch * 4 + kcL * 2 + h] = *(const unsigned*)
                    (Ab + (size_t)(rA0 + h * 16) * 256 + ch * 32 + kcL * 16 + q * 4);

    f32x4 acc[2][8];
#pragma unroll
    for (int mt = 0; mt < 2; ++mt)
#pragma unroll
        for (int nt = 0; nt < 8; ++nt) acc[mt][nt] = (f32x4){0.f, 0.f, 0.f, 0.f};

    // prologue: B chunks 0,1 -> buffers 0,1 (XOR-swizzled on global source)
#pragma unroll
    for (int c = 0; c < 2; ++c)
#pragma unroll
        for (int j = 0; j < 2; ++j) {
            int p = t + 512 * j; int f = p >> 3;   // 1024 slots: 128f x 128B
            gload16((const char*)hb + (size_t)f * 1024 + c * 128
                        + (((p & 7) ^ (f & 7)) << 4),
                    smem + c * 16384 + p * 16);
        }
#pragma unroll
    for (int ch = 0; ch < 8; ++ch) {
        char* Bsc = smem + (ch % 3) * 16384;
        if (ch < 6) {                          // issue chunk ch+2
            int cn = ch + 2;
            char* Bsn = smem + (cn % 3) * 16384;
#pragma unroll
            for (int j = 0; j < 2; ++j) {
                int p = t + 512 * j; int f = p >> 3;
                gload16((const char*)hb + (size_t)f * 1024 + cn * 128
                            + (((p & 7) ^ (f & 7)) << 4),
                        Bsn + p * 16);
            }
        }
        // counted wait: chunk ch landed; up to 2 newer chunks stay in flight
        if (ch < 6)      asm volatile("s_waitcnt vmcnt(4)" ::: "memory");
        else if (ch < 7) asm volatile("s_waitcnt vmcnt(2)" ::: "memory");
        else             asm volatile("s_waitcnt vmcnt(0)" ::: "memory");
        __builtin_amdgcn_s_barrier();          // chunk ch visible to all waves
#pragma unroll
        for (int kcL = 0; kcL < 2; ++kcL) {
            bf16x8 af0 = cvt8n(aA[ch * 4 + kcL * 2 + 0]);
            bf16x8 af1 = cvt8n(aA[ch * 4 + kcL * 2 + 1]);
#pragma unroll
            for (int nt = 0; nt < 8; ++nt) {
                int f = nt * 16 + ln;
                int sB = f * 8 + ((kcL * 4 + q) ^ (f & 7));
                bf16x8 bf = *(const bf16x8*)(Bsc + sB * 16);
                acc[0][nt] = __builtin_amdgcn_mfma_f32_16x16x32_bf16(af0, bf, acc[0][nt], 0, 0, 0);
                acc[1][nt] = __builtin_amdgcn_mfma_f32_16x16x32_bf16(af1, bf, acc[1][nt], 0, 0, 0);
            }
        }
        __builtin_amdgcn_s_barrier();          // reads of buf[ch%3] done (reuse)
    }
    // P = pooled + (1+eps)*h_self -> bf16 P-tile [row][feat], stride 272
    float ep = 1.f + eps[0];
#pragma unroll
    for (int mt = 0; mt < 2; ++mt) {
        int rl0 = w * 32 + mt * 16 + q * 4;   // local C rows rl0..rl0+3
        int mb0 = hf * 256 + rl0;             // global node index
#pragma unroll
        for (int nt = 0; nt < 8; ++nt) {
            int f = nt * 16 + ln;
            uint2 sv = *(const uint2*)(hb + (size_t)f * 512 + mb0);   // self h
            float s0 = __uint_as_float(sv.x << 16);
            float s1 = __uint_as_float(sv.x & 0xffff0000u);
            float s2 = __uint_as_float(sv.y << 16);
            float s3 = __uint_as_float(sv.y & 0xffff0000u);
            f32x4 a = acc[mt][nt];
            *(u16*)(Ps + (rl0 + 0) * 272 + f * 2) = (u16)bf1(fmaf(ep, s0, a[0]));
            *(u16*)(Ps + (rl0 + 1) * 272 + f * 2) = (u16)bf1(fmaf(ep, s1, a[1]));
            *(u16*)(Ps + (rl0 + 2) * 272 + f * 2) = (u16)bf1(fmaf(ep, s2, a[2]));
            *(u16*)(Ps + (rl0 + 3) * 272 + f * 2) = (u16)bf1(fmaf(ep, s3, a[3]));
        }
    }
    __syncthreads();                          // P visible to all waves
    // Phase 2: h'(256x128) = relu(P @ W + b); A-frags from Ps, B from Wt (L1)
    f32x4 acc2[2][8];
#pragma unroll
    for (int mt = 0; mt < 2; ++mt)
#pragma unroll
        for (int nt = 0; nt < 8; ++nt) acc2[mt][nt] = (f32x4){0.f, 0.f, 0.f, 0.f};
#pragma unroll
    for (int ks = 0; ks < 4; ++ks) {
        bf16x8 af0 = *(const bf16x8*)(Ps + rA0 * 272 + ks * 64 + q * 16);
        bf16x8 af1 = *(const bf16x8*)(Ps + (rA0 + 16) * 272 + ks * 64 + q * 16);
#pragma unroll
        for (int nt = 0; nt < 8; ++nt) {
            bf16x8 bf = *(const bf16x8*)(wt + (size_t)(nt * 16 + ln) * 128 + ks * 32 + q * 8);
            acc2[0][nt] = __builtin_amdgcn_mfma_f32_16x16x32_bf16(af0, bf, acc2[0][nt], 0, 0, 0);
            acc2[1][nt] = __builtin_amdgcn_mfma_f32_16x16x32_bf16(af1, bf, acc2[1][nt], 0, 0, 0);
        }
    }
    __syncthreads();                          // all P reads done; reuse as Os
    // epilogue: relu + bias, stage transposed [out-feat][256 nodes], stride 528
#pragma unroll
    for (int mt = 0; mt < 2; ++mt) {
        int rl0 = w * 32 + mt * 16 + q * 4;
#pragma unroll
        for (int nt = 0; nt < 8; ++nt) {
            int n = nt * 16 + ln;
            float bv = bias[n];
            f32x4 a = acc2[mt][nt];
            *(uint2*)(Ps + n * 528 + rl0 * 2) =
                make_uint2(pack_bf2(fmaxf(a[0] + bv, 0.f), fmaxf(a[1] + bv, 0.f)),
                           pack_bf2(fmaxf(a[2] + bv, 0.f), fmaxf(a[3] + bv, 0.f)));
        }
    }
    __syncthreads();
    u16* ho = hTo + (size_t)g * 65536 + hf * 256;
#pragma unroll
    for (int j = 0; j < 8; ++j) {
        int idx = t + 512 * j;                // 4096 uint4s: 128 f x 512 B
        int f = idx >> 5, piece = idx & 31;
        uint4 v = *(const uint4*)(Ps + f * 528 + piece * 16);
        *(uint4*)((char*)(ho + (size_t)f * 512) + piece * 16) = v;
    }
}

// readout from hT: hg[f] = row-sum; z = relu(hg@fc1+b1); softmax(z@fc2+b2)
__global__ __launch_bounds__(128) void k_r(const u16* __restrict__ hT,
                                           const float* __restrict__ fc1w,
                                           const float* __restrict__ fc1b,
                                           const float* __restrict__ fc2w,
                                           const float* __restrict__ fc2b,
                                           float* __restrict__ out) {
    __shared__ float hg[128], z[128], lg[10];
    int g = blockIdx.x, t = threadIdx.x;
    const uint4* row = (const uint4*)(hT + (size_t)g * 65536 + (size_t)t * 512);
    float acc = 0.f;
#pragma unroll 4
    for (int i = 0; i < 64; ++i) {
        uint4 u = row[i];
        acc += __uint_as_float(u.x << 16) + __uint_as_float(u.x & 0xffff0000u);
        acc += __uint_as_float(u.y << 16) + __uint_as_float(u.y & 0xffff0000u);
        acc += __uint_as_float(u.z << 16) + __uint_as_float(u.z & 0xffff0000u);
        acc += __uint_as_float(u.w << 16) + __uint_as_float(u.w & 0xffff0000u);
    }
    hg[t] = acc;
    __syncthreads();
    float a1 = fc1b[t];
#pragma unroll 4
    for (int k = 0; k < 128; ++k) a1 = fmaf(hg[k], fc1w[k * 128 + t], a1);
    z[t] = fmaxf(a1, 0.f);
    __syncthreads();
    if (t < 10) {
        float l2 = fc2b[t];
        for (int k = 0; k < 128; ++k) l2 = fmaf(z[k], fc2w[k * 10 + t], l2);
        lg[t] = l2;
    }
    __syncthreads();
    if (t < 10) {
        float m = lg[0];
        for (int c = 1; c < 10; ++c) m = fmaxf(m, lg[c]);
        float ssum = 0.f;
        for (int c = 0; c < 10; ++c) ssum += expf(lg[c] - m);
        out[g * 10 + t] = expf(lg[t] - m) / ssum;
    }
}

extern "C" void kernel_launch(void* const* d_in, const int* in_sizes, int n_in,
                              void* d_out, int out_size, void* d_ws, size_t ws_size,
                              hipStream_t stream) {
    const float* x    = (const float*)d_in[0];
    const float* eps  = (const float*)d_in[1];
    const float* W    = (const float*)d_in[2];
    const float* b    = (const float*)d_in[3];
    const float* fc1w = (const float*)d_in[4];
    const float* fc1b = (const float*)d_in[5];
    const float* fc2w = (const float*)d_in[6];
    const float* fc2b = (const float*)d_in[7];
    const int*   src  = (const int*)d_in[8];
    const int*   dst  = (const int*)d_in[9];
    int E = in_sizes[8];
    int halfE = E >> 1;

    char* ws  = (char*)d_ws;
    unsigned char* Abuf = (unsigned char*)(ws + OFF_A);
    u16*  wtb = (u16*)(ws + OFF_WT);
    u16*  hta = (u16*)(ws + OFF_HTA);
    u16*  htb = (u16*)(ws + OFF_HTB);
    float* out = (float*)d_out;

    k_prep<<<1344, 256, 0, stream>>>(x, hta, W, wtb);
    k_adense<<<GNUM, 1024, 0, stream>>>(src, dst, (unsigned*)Abuf, halfE);

    u16* cur = hta;
    u16* nxt = htb;
    for (int l = 0; l < 5; ++l) {
        k_layer<<<GNUM * 2, 512, 0, stream>>>(cur, nxt, Abuf,
                                              wtb + l * 128 * 128, b + l * 128, eps + l);
        u16* tmp = cur; cur = nxt; nxt = tmp;
    }
    k_r<<<GNUM, 128, 0, stream>>>(cur, fc1w, fc1b, fc2w, fc2b, out);
}